// Round 1
// baseline (87.727 us; speedup 1.0000x reference)
//
#include <hip/hip_runtime.h>

#define HF 64
#define WF 64
#define CCH 512
// grid points per axis = 8, output = 7x7 per (k,c)

// ---------------- transpose NCHW -> NHWC (features are only 16.7 MB) --------
__global__ __launch_bounds__(256) void nchw_to_nhwc(const float* __restrict__ src,
                                                    float* __restrict__ dst) {
    __shared__ float tile[32][33];
    const int hw0 = blockIdx.x * 32;
    const int c0  = blockIdx.y * 32;
    const int b   = blockIdx.z;
    const int tx = threadIdx.x & 31;
    const int ty = threadIdx.x >> 5;   // 0..7
    const float* s = src + (size_t)b * CCH * (HF * WF);
    float*       d = dst + (size_t)b * (HF * WF) * CCH;
#pragma unroll
    for (int i = 0; i < 32; i += 8)
        tile[ty + i][tx] = s[(size_t)(c0 + ty + i) * (HF * WF) + hw0 + tx];
    __syncthreads();
#pragma unroll
    for (int i = 0; i < 32; i += 8)
        d[(size_t)(hw0 + ty + i) * CCH + c0 + tx] = tile[tx][ty + i];
}

// ---------------- main RoIAlign+avg kernel ----------------------------------
// One block = (roi k, channel chunk of 256). Thread = one channel.
// NHWC=true: gather loads are coalesced across channels (lane = c).
template <bool NHWC>
__global__ __launch_bounds__(256) void roialign_main(const float* __restrict__ ft,
                                                     const float* __restrict__ rois,
                                                     float* __restrict__ out) {
    __shared__ __align__(16) float sbuf[256 * 49];

    const int blk   = blockIdx.x;
    const int k     = blk >> 1;
    const int chunk = blk & 1;
    const int tid   = threadIdx.x;
    const int c     = chunk * 256 + tid;

    const float* r = rois + (size_t)k * 5;
    const int   b  = (int)r[0];
    const float x1 = r[1] * 0.0625f;
    const float y1 = r[2] * 0.0625f;
    const float x2 = r[3] * 0.0625f;
    const float y2 = r[4] * 0.0625f;
    const float bin_h = fmaxf(y2 - y1, 0.0f) / 7.0f;
    const float bin_w = fmaxf(x2 - x1, 0.0f) / 7.0f;

    int   hi_[8]; float hr_[8]; float fvh[8];
    int   wi_[8]; float wr_[8]; float fvw[8];
#pragma unroll
    for (int i = 0; i < 8; ++i) {
        float h  = y1 + (float)i * bin_h;
        float hs = fminf(floorf(h), 62.0f);
        hr_[i]   = h - hs;                                  // note: uses hs, not clipped hi
        hi_[i]   = (int)fminf(fmaxf(hs, 0.0f), 62.0f);
        fvh[i]   = (h >= 0.0f && h < 64.0f) ? 1.0f : 0.0f;
        float w  = x1 + (float)i * bin_w;
        float ws = fminf(floorf(w), 62.0f);
        wr_[i]   = w - ws;
        wi_[i]   = (int)fminf(fmaxf(ws, 0.0f), 62.0f);
        fvw[i]   = (w >= 0.0f && w < 64.0f) ? 1.0f : 0.0f;
    }

    float  prev[8];
    float* srow = sbuf + tid * 49;

#pragma unroll
    for (int i = 0; i < 8; ++i) {
        float cur[8];
#pragma unroll
        for (int j = 0; j < 8; ++j) {
            size_t o00, dw, dh;
            if (NHWC) {
                o00 = (size_t)((b * HF + hi_[i]) * WF + wi_[j]) * CCH + c;
                dw  = CCH;                 // w+1
                dh  = (size_t)WF * CCH;    // h+1
            } else {
                o00 = (size_t)(b * CCH + c) * (HF * WF) + hi_[i] * WF + wi_[j];
                dw  = 1;
                dh  = WF;
            }
            const float v00 = ft[o00];
            const float v01 = ft[o00 + dw];
            const float v10 = ft[o00 + dh];
            const float v11 = ft[o00 + dh + dw];
            const float top = v00 + wr_[j] * (v01 - v00);
            const float bot = v10 + wr_[j] * (v11 - v10);
            const float v   = top + hr_[i] * (bot - top);
            cur[j] = v * (fvh[i] * fvw[j]);
        }
        if (i > 0) {
#pragma unroll
            for (int j = 0; j < 7; ++j)
                srow[(i - 1) * 7 + j] =
                    0.25f * (prev[j] + prev[j + 1] + cur[j] + cur[j + 1]);
        }
#pragma unroll
        for (int j = 0; j < 8; ++j) prev[j] = cur[j];
    }

    __syncthreads();

    // coalesced float4 writeout of the 256x49 tile (12544 floats = 3136 float4)
    float* obase = out + ((size_t)k * CCH + (size_t)chunk * 256) * 49;
    const float4* s4 = reinterpret_cast<const float4*>(sbuf);
    float4*       o4 = reinterpret_cast<float4*>(obase);
    for (int idx = tid; idx < 3136; idx += 256) o4[idx] = s4[idx];
}

extern "C" void kernel_launch(void* const* d_in, const int* in_sizes, int n_in,
                              void* d_out, int out_size, void* d_ws, size_t ws_size,
                              hipStream_t stream) {
    const float* feat = (const float*)d_in[0];
    const float* rois = (const float*)d_in[1];
    float*       out  = (float*)d_out;

    const int B = in_sizes[0] / (CCH * HF * WF);
    const int K = in_sizes[1] / 5;

    const size_t tbytes = (size_t)B * CCH * HF * WF * sizeof(float);
    if (ws_size >= tbytes) {
        float* ftr = (float*)d_ws;
        dim3 tg((HF * WF) / 32, CCH / 32, B);
        nchw_to_nhwc<<<tg, 256, 0, stream>>>(feat, ftr);
        roialign_main<true><<<K * 2, 256, 0, stream>>>(ftr, rois, out);
    } else {
        roialign_main<false><<<K * 2, 256, 0, stream>>>(feat, rois, out);
    }
}

// Round 2
// 72.965 us; speedup vs baseline: 1.2023x; 1.2023x over previous
//
#include <hip/hip_runtime.h>

#define HF 64
#define WF 64
#define CCH 512

// f32 -> bf16 round-to-nearest-even
__device__ __forceinline__ unsigned short f32_to_bf16(float f) {
    unsigned int x = __float_as_uint(f);
    unsigned int r = (x + 0x7FFFu + ((x >> 16) & 1u)) >> 16;
    return (unsigned short)r;
}
__device__ __forceinline__ float bf16_to_f32(unsigned short u) {
    return __uint_as_float(((unsigned int)u) << 16);
}

// ---------------- transpose+convert NCHW f32 -> NHWC bf16 -------------------
__global__ __launch_bounds__(256) void nchw_to_nhwc_bf16(const float* __restrict__ src,
                                                         unsigned short* __restrict__ dst) {
    __shared__ float tile[32][33];
    const int hw0 = blockIdx.x * 32;
    const int c0  = blockIdx.y * 32;
    const int b   = blockIdx.z;
    const int tx  = threadIdx.x & 31;
    const int ty  = threadIdx.x >> 5;   // 0..7
    const float*    s = src + (size_t)b * CCH * (HF * WF);
    unsigned short* d = dst + (size_t)b * (HF * WF) * CCH;
#pragma unroll
    for (int i = 0; i < 32; i += 8)
        tile[ty + i][tx] = s[(size_t)(c0 + ty + i) * (HF * WF) + hw0 + tx];
    __syncthreads();
#pragma unroll
    for (int i = 0; i < 32; i += 8)
        d[(size_t)(hw0 + ty + i) * CCH + c0 + tx] = f32_to_bf16(tile[tx][ty + i]);
}

// ---------------- main RoIAlign+avg kernel (NHWC bf16 gather) ---------------
// One block = (roi k, channel chunk of 256). Thread = one channel.
__global__ __launch_bounds__(256) void roialign_bf16(const unsigned short* __restrict__ ft,
                                                     const float* __restrict__ rois,
                                                     float* __restrict__ out) {
    __shared__ __align__(16) float sbuf[256 * 49];

    const int blk   = blockIdx.x;
    const int k     = blk >> 1;
    const int chunk = blk & 1;
    const int tid   = threadIdx.x;
    const int c     = chunk * 256 + tid;

    const float* r = rois + (size_t)k * 5;
    const int   b  = (int)r[0];
    const float x1 = r[1] * 0.0625f;
    const float y1 = r[2] * 0.0625f;
    const float x2 = r[3] * 0.0625f;
    const float y2 = r[4] * 0.0625f;
    const float bin_h = fmaxf(y2 - y1, 0.0f) / 7.0f;
    const float bin_w = fmaxf(x2 - x1, 0.0f) / 7.0f;

    int   hi_[8]; float hr_[8]; float fvh[8];
    int   wi_[8]; float wr_[8]; float fvw[8];
#pragma unroll
    for (int i = 0; i < 8; ++i) {
        float h  = y1 + (float)i * bin_h;
        float hs = fminf(floorf(h), 62.0f);
        hr_[i]   = h - hs;
        hi_[i]   = (int)fminf(fmaxf(hs, 0.0f), 62.0f);
        fvh[i]   = (h >= 0.0f && h < 64.0f) ? 1.0f : 0.0f;
        float w  = x1 + (float)i * bin_w;
        float ws = fminf(floorf(w), 62.0f);
        wr_[i]   = w - ws;
        wi_[i]   = (int)fminf(fmaxf(ws, 0.0f), 62.0f);
        fvw[i]   = (w >= 0.0f && w < 64.0f) ? 1.0f : 0.0f;
    }

    float  prev[8];
    float* srow = sbuf + tid * 49;

#pragma unroll
    for (int i = 0; i < 8; ++i) {
        float cur[8];
#pragma unroll
        for (int j = 0; j < 8; ++j) {
            const unsigned int o00 =
                (unsigned int)(((b * HF + hi_[i]) * WF + wi_[j]) * CCH + c);
            const float v00 = bf16_to_f32(ft[o00]);
            const float v01 = bf16_to_f32(ft[o00 + CCH]);
            const float v10 = bf16_to_f32(ft[o00 + WF * CCH]);
            const float v11 = bf16_to_f32(ft[o00 + WF * CCH + CCH]);
            const float top = v00 + wr_[j] * (v01 - v00);
            const float bot = v10 + wr_[j] * (v11 - v10);
            const float v   = top + hr_[i] * (bot - top);
            cur[j] = v * (fvh[i] * fvw[j]);
        }
        if (i > 0) {
#pragma unroll
            for (int j = 0; j < 7; ++j)
                srow[(i - 1) * 7 + j] =
                    0.25f * (prev[j] + prev[j + 1] + cur[j] + cur[j + 1]);
        }
#pragma unroll
        for (int j = 0; j < 8; ++j) prev[j] = cur[j];
    }

    __syncthreads();

    // coalesced float4 writeout of the 256x49 tile (12544 floats = 3136 float4)
    float* obase = out + ((size_t)k * CCH + (size_t)chunk * 256) * 49;
    const float4* s4 = reinterpret_cast<const float4*>(sbuf);
    float4*       o4 = reinterpret_cast<float4*>(obase);
    for (int idx = tid; idx < 3136; idx += 256) o4[idx] = s4[idx];
}

// ---------------- fallback: direct NCHW f32 (if ws too small) ---------------
__global__ __launch_bounds__(256) void roialign_f32_nchw(const float* __restrict__ ft,
                                                         const float* __restrict__ rois,
                                                         float* __restrict__ out) {
    __shared__ __align__(16) float sbuf[256 * 49];
    const int blk   = blockIdx.x;
    const int k     = blk >> 1;
    const int chunk = blk & 1;
    const int tid   = threadIdx.x;
    const int c     = chunk * 256 + tid;

    const float* r = rois + (size_t)k * 5;
    const int   b  = (int)r[0];
    const float x1 = r[1] * 0.0625f;
    const float y1 = r[2] * 0.0625f;
    const float x2 = r[3] * 0.0625f;
    const float y2 = r[4] * 0.0625f;
    const float bin_h = fmaxf(y2 - y1, 0.0f) / 7.0f;
    const float bin_w = fmaxf(x2 - x1, 0.0f) / 7.0f;

    int hi_[8]; float hr_[8]; float fvh[8];
    int wi_[8]; float wr_[8]; float fvw[8];
#pragma unroll
    for (int i = 0; i < 8; ++i) {
        float h  = y1 + (float)i * bin_h;
        float hs = fminf(floorf(h), 62.0f);
        hr_[i] = h - hs;
        hi_[i] = (int)fminf(fmaxf(hs, 0.0f), 62.0f);
        fvh[i] = (h >= 0.0f && h < 64.0f) ? 1.0f : 0.0f;
        float w  = x1 + (float)i * bin_w;
        float ws = fminf(floorf(w), 62.0f);
        wr_[i] = w - ws;
        wi_[i] = (int)fminf(fmaxf(ws, 0.0f), 62.0f);
        fvw[i] = (w >= 0.0f && w < 64.0f) ? 1.0f : 0.0f;
    }

    float prev[8];
    float* srow = sbuf + tid * 49;
#pragma unroll
    for (int i = 0; i < 8; ++i) {
        float cur[8];
#pragma unroll
        for (int j = 0; j < 8; ++j) {
            size_t o00 = (size_t)(b * CCH + c) * (HF * WF) + hi_[i] * WF + wi_[j];
            const float v00 = ft[o00];
            const float v01 = ft[o00 + 1];
            const float v10 = ft[o00 + WF];
            const float v11 = ft[o00 + WF + 1];
            const float top = v00 + wr_[j] * (v01 - v00);
            const float bot = v10 + wr_[j] * (v11 - v10);
            const float v   = top + hr_[i] * (bot - top);
            cur[j] = v * (fvh[i] * fvw[j]);
        }
        if (i > 0) {
#pragma unroll
            for (int j = 0; j < 7; ++j)
                srow[(i - 1) * 7 + j] =
                    0.25f * (prev[j] + prev[j + 1] + cur[j] + cur[j + 1]);
        }
#pragma unroll
        for (int j = 0; j < 8; ++j) prev[j] = cur[j];
    }
    __syncthreads();
    float* obase = out + ((size_t)k * CCH + (size_t)chunk * 256) * 49;
    const float4* s4 = reinterpret_cast<const float4*>(sbuf);
    float4*       o4 = reinterpret_cast<float4*>(obase);
    for (int idx = tid; idx < 3136; idx += 256) o4[idx] = s4[idx];
}

extern "C" void kernel_launch(void* const* d_in, const int* in_sizes, int n_in,
                              void* d_out, int out_size, void* d_ws, size_t ws_size,
                              hipStream_t stream) {
    const float* feat = (const float*)d_in[0];
    const float* rois = (const float*)d_in[1];
    float*       out  = (float*)d_out;

    const int B = in_sizes[0] / (CCH * HF * WF);
    const int K = in_sizes[1] / 5;

    const size_t tbytes = (size_t)B * CCH * HF * WF * sizeof(unsigned short);
    if (ws_size >= tbytes) {
        unsigned short* ftr = (unsigned short*)d_ws;
        dim3 tg((HF * WF) / 32, CCH / 32, B);
        nchw_to_nhwc_bf16<<<tg, 256, 0, stream>>>(feat, ftr);
        roialign_bf16<<<K * 2, 256, 0, stream>>>(ftr, rois, out);
    } else {
        roialign_f32_nchw<<<K * 2, 256, 0, stream>>>(feat, rois, out);
    }
}